// Round 6
// baseline (585.787 us; speedup 1.0000x reference)
//
#include <hip/hip_runtime.h>
#include <math.h>

#define NCH 48
#define NB 16
#define PLANE 16384
#define NPLANES 768

// d_ws float layout
#define WS_PSUM  0
#define WS_PSQ   768
#define WS_SCALE 1536
#define WS_SHIFT 1584
#define WS_TAB   1632   // [src 4][tgt 4][6 coefs]
#define WS_CONST 1728   // [4]

// compile-time for: every per-thread array index is a literal (rule #20)
template<int I> struct ic { static constexpr int v = I; };
template<int S, int E, typename F>
__device__ __forceinline__ void sfor(F&& f) {
  if constexpr (S < E) { f(ic<S>{}); sfor<S + 1, E>(f); }
}

typedef float f16v __attribute__((ext_vector_type(16)));

// ---------------- stage A: per-plane partial sums ----------------
__global__ __launch_bounds__(256) void stats_kernel(const float* __restrict__ x,
                                                    float* __restrict__ ws) {
  int p = blockIdx.x;
  int t = threadIdx.x;
  const float4* x4 = (const float4*)x + (size_t)p * 4096;
  float s = 0.f, q = 0.f;
  #pragma unroll
  for (int k = 0; k < 16; ++k) {
    float4 v = x4[k * 256 + t];
    s += v.x + v.y + v.z + v.w;
    q += v.x * v.x + v.y * v.y + v.z * v.z + v.w * v.w;
  }
  #pragma unroll
  for (int off = 32; off > 0; off >>= 1) {
    s += __shfl_xor(s, off, 64);
    q += __shfl_xor(q, off, 64);
  }
  __shared__ float red[8];
  int wid = t >> 6, lane = t & 63;
  if (lane == 0) { red[wid] = s; red[4 + wid] = q; }
  __syncthreads();
  if (t == 0) {
    ws[WS_PSUM + p] = red[0] + red[1] + red[2] + red[3];
    ws[WS_PSQ  + p] = red[4] + red[5] + red[6] + red[7];
  }
}

// ---------------- stage B: BN params + merged weight table ----------------
__global__ void prep_kernel(const float* __restrict__ gamma, const float* __restrict__ beta,
                            const float* __restrict__ alphas, float* __restrict__ ws) {
  int t = threadIdx.x;
  if (t < NCH) {
    float s = 0.f, q = 0.f;
    for (int b = 0; b < NB; ++b) {
      s += ws[WS_PSUM + b * NCH + t];
      q += ws[WS_PSQ  + b * NCH + t];
    }
    const float inv = 1.0f / ((float)NB * PLANE);
    float mean = s * inv;
    float var  = q * inv - mean * mean;
    float sc = gamma[t] * rsqrtf(var + 1e-5f);
    ws[WS_SCALE + t] = sc;
    ws[WS_SHIFT + t] = beta[t] - mean * sc;
  }
  if (t == 0) {
    float w[14][7];
    for (int r = 0; r < 14; ++r) {
      float m = -1e30f;
      for (int k = 0; k < 7; ++k) m = fmaxf(m, alphas[r * 7 + k]);
      float sum = 0.f;
      for (int k = 0; k < 7; ++k) { float e = expf(alphas[r * 7 + k] - m); w[r][k] = e; sum += e; }
      float is = 1.0f / sum;
      for (int k = 0; k < 7; ++k) w[r][k] *= is;
    }
    for (int i = 0; i < 96; ++i) ws[WS_TAB + i] = 0.f;
    for (int i = 0; i < 4;  ++i) ws[WS_CONST + i] = 0.f;
    const int map[14][2] = {
      {0,0},{0,0},
      {0,1},{0,1},{1,1},
      {0,2},{0,2},{1,2},{2,2},
      {0,3},{0,3},{1,3},{2,3},{3,3}
    };
    for (int r = 0; r < 14; ++r) {
      int p = map[r][0], tg = map[r][1];
      float* cf = ws + WS_TAB + (p * 4 + tg) * 6;
      cf[0] += w[r][0] - w[r][2];       // identity
      cf[1] += w[r][1] * (1.0f / 9.0f); // blur (/9 folded)
      cf[2] += w[r][3];                 // fliplr
      cf[3] += w[r][4];                 // flipud
      cf[4] += w[r][5];                 // roll(+4,+4)
      cf[5] += w[r][6];                 // rot90
      ws[WS_CONST + tg] += w[r][2];     // constant w2
    }
  }
}

// ---------------- main fused kernel ----------------
// LDS swizzle: float4-block index for (row i, block bj): bj ^= (i>>2)&7.
__device__ __forceinline__ int swb(int i, int bj) {
  return (i << 5) + (bj ^ ((i >> 2) & 7));
}
__device__ __forceinline__ float ldsw(const float* l, int i, int j) {
  int bj = j >> 2;
  return l[(i << 7) + (((bj ^ ((i >> 2) & 7)) << 2) | (j & 3))];
}

__device__ __forceinline__ void ldcf(float (&cf)[6], const float* __restrict__ wsf,
                                     int p, int tg) {
  sfor<0, 6>([&](auto K) { cf[K.v] = wsf[WS_TAB + (p * 4 + tg) * 6 + K.v]; });
}

// One full-plane gather applying the 6-op linear stencil from LDS source to
// NT accumulator vectors (NT=1 or 2). All acc indices compile-time.
template<int NT>
__device__ __forceinline__ void gather(const float4* l4, const float* l1,
    int oi, int oj, int ty, int tx,
    const float (&cfA)[6], const float (&cfB)[6], f16v& A, f16v& B)
{
  auto upd = [&](auto IDX, auto OP, float v) {
    A[IDX.v] += cfA[OP.v] * v;
    if constexpr (NT == 2) B[IDX.v] += cfB[OP.v] * v;
  };
  // ---- identity + box blur (6 rows, reflect borders) ----
  int cLo = (tx == 0)  ? 1   : oj - 1;
  int cHi = (tx == 31) ? 126 : oj + 4;
  float hs[3][4];
  sfor<0, 6>([&](auto RC) {
    constexpr int r = RC.v;
    int ri = oi - 1 + r;
    ri = (ri < 0) ? 1 : ((ri > 127) ? 126 : ri);
    float4 mid = l4[swb(ri, tx)];
    float lo = ldsw(l1, ri, cLo);
    float hi = ldsw(l1, ri, cHi);
    if constexpr (r >= 1 && r <= 4) {
      constexpr int a = r - 1;
      upd(ic<a * 4 + 0>{}, ic<0>{}, mid.x);
      upd(ic<a * 4 + 1>{}, ic<0>{}, mid.y);
      upd(ic<a * 4 + 2>{}, ic<0>{}, mid.z);
      upd(ic<a * 4 + 3>{}, ic<0>{}, mid.w);
    }
    hs[r % 3][0] = lo    + mid.x + mid.y;
    hs[r % 3][1] = mid.x + mid.y + mid.z;
    hs[r % 3][2] = mid.y + mid.z + mid.w;
    hs[r % 3][3] = mid.z + mid.w + hi;
    if constexpr (r >= 2) {
      constexpr int a = r - 2;
      sfor<0, 4>([&](auto QC) {
        constexpr int bq = QC.v;
        float bb = hs[0][bq] + hs[1][bq] + hs[2][bq];
        upd(ic<a * 4 + bq>{}, ic<1>{}, bb);
      });
    }
  });
  // ---- fliplr ----
  sfor<0, 4>([&](auto AC) {
    constexpr int a = AC.v;
    float4 m = l4[swb(oi + a, 31 - tx)];
    upd(ic<a * 4 + 0>{}, ic<2>{}, m.w);
    upd(ic<a * 4 + 1>{}, ic<2>{}, m.z);
    upd(ic<a * 4 + 2>{}, ic<2>{}, m.y);
    upd(ic<a * 4 + 3>{}, ic<2>{}, m.x);
  });
  // ---- flipud ----
  sfor<0, 4>([&](auto AC) {
    constexpr int a = AC.v;
    float4 m = l4[swb(127 - oi - a, tx)];
    upd(ic<a * 4 + 0>{}, ic<3>{}, m.x);
    upd(ic<a * 4 + 1>{}, ic<3>{}, m.y);
    upd(ic<a * 4 + 2>{}, ic<3>{}, m.z);
    upd(ic<a * 4 + 3>{}, ic<3>{}, m.w);
  });
  // ---- roll(+4,+4) ----
  sfor<0, 4>([&](auto AC) {
    constexpr int a = AC.v;
    float4 m = l4[swb((oi + a - 4) & 127, (tx + 31) & 31)];
    upd(ic<a * 4 + 0>{}, ic<4>{}, m.x);
    upd(ic<a * 4 + 1>{}, ic<4>{}, m.y);
    upd(ic<a * 4 + 2>{}, ic<4>{}, m.z);
    upd(ic<a * 4 + 3>{}, ic<4>{}, m.w);
  });
  // ---- rot90 (k=1): out[i][j] = src[j][127-i] ----
  sfor<0, 4>([&](auto RB) {
    constexpr int rb = RB.v;
    float4 m = l4[swb(oj + rb, 31 - ty)];
    upd(ic< 0 + rb>{}, ic<5>{}, m.w);
    upd(ic< 4 + rb>{}, ic<5>{}, m.z);
    upd(ic< 8 + rb>{}, ic<5>{}, m.y);
    upd(ic<12 + rb>{}, ic<5>{}, m.x);
  });
}

#define WRITEV(V, T)                                                            \
  sfor<0, 4>([&](auto RC) {                                                     \
    constexpr int r = RC.v;                                                     \
    float4 v; v.x = V[r*4+0]; v.y = V[r*4+1]; v.z = V[r*4+2]; v.w = V[r*4+3];   \
    out4[(pbase + T * NCH) * 4096 + (oi + r) * 32 + tx] = v;                    \
  })
#define STASHV(L4, V)                                                           \
  sfor<0, 4>([&](auto RC) {                                                     \
    constexpr int r = RC.v;                                                     \
    float4 v; v.x = V[r*4+0]; v.y = V[r*4+1]; v.z = V[r*4+2]; v.w = V[r*4+3];   \
    L4[swb(oi + r, tx)] = v;                                                    \
  })

// Two-round schedule: peak live accumulators = 3x f16v (48 floats) instead of
// the 4x16 array that the backend insisted on scratching (R2-R5: VGPR stuck
// at 64, ~1 GB spill traffic). 2 LDS plane buffers (128 KB) -> 1 block/CU.
__global__ __launch_bounds__(1024)
__attribute__((amdgpu_waves_per_eu(4, 4)))
void main_kernel(const float* __restrict__ x,
    const float* __restrict__ wsf, float* __restrict__ out)
{
  __shared__ float lds[2 * PLANE];        // 128 KB
  float* b0 = lds;
  float* b1 = lds + PLANE;
  float4* l40 = (float4*)b0;
  float4* l41 = (float4*)b1;
  int bx = blockIdx.x;
  int b = bx / NCH, c = bx % NCH;
  int tid = threadIdx.x;
  int ty = tid >> 5, tx = tid & 31;
  int oi = ty << 2, oj = tx << 2;
  float4* out4 = (float4*)out;
  const size_t pbase = (size_t)b * 192 + c;

  // stage s = BN(x) into buf0
  float sc = wsf[WS_SCALE + c], sh = wsf[WS_SHIFT + c];
  const float4* x4 = (const float4*)x + (size_t)bx * 4096;
  sfor<0, 4>([&](auto RC) {
    constexpr int r = RC.v;
    float4 v = x4[(oi + r) * 32 + tx];
    float4 sv;
    sv.x = v.x * sc + sh; sv.y = v.y * sc + sh;
    sv.z = v.z * sc + sh; sv.w = v.w * sc + sh;
    l40[swb(oi + r, tx)] = sv;
  });

  float cf1[6], cf2[6];
  f16v A, B;                               // round 1: A = s2 acc, B = s3 acc
  {
    float c0 = wsf[WS_CONST + 0], c1 = wsf[WS_CONST + 1];
    sfor<0, 16>([&](auto K) { A[K.v] = c0; B[K.v] = c1; });
  }
  __syncthreads();

  // gather 1: src s (buf0) -> s2, s3
  ldcf(cf1, wsf, 0, 0); ldcf(cf2, wsf, 0, 1);
  gather<2>(l40, b0, oi, oj, ty, tx, cf1, cf2, A, B);
  WRITEV(A, 0);
  STASHV(l41, A);                          // s2 -> buf1 (disjoint from buf0 reads)
  __syncthreads();

  // gather 2: src s2 (buf1) -> s3
  ldcf(cf1, wsf, 1, 1);
  gather<1>(l41, b1, oi, oj, ty, tx, cf1, cf1, B, B);
  WRITEV(B, 1);                            // keep s3 in B (stash later)

  // round 2: C = s4 acc, A reused = s5 acc
  f16v C;
  {
    float c2 = wsf[WS_CONST + 2], c3 = wsf[WS_CONST + 3];
    sfor<0, 16>([&](auto K) { C[K.v] = c2; A[K.v] = c3; });
  }

  // gather 3: src s (buf0) -> s4, s5
  ldcf(cf1, wsf, 0, 2); ldcf(cf2, wsf, 0, 3);
  gather<2>(l40, b0, oi, oj, ty, tx, cf1, cf2, C, A);
  // gather 4: src s2 (buf1) -> s4, s5
  ldcf(cf1, wsf, 1, 2); ldcf(cf2, wsf, 1, 3);
  gather<2>(l41, b1, oi, oj, ty, tx, cf1, cf2, C, A);

  __syncthreads();                         // all buf0 (s) reads done
  STASHV(l40, B);                          // s3 -> buf0
  __syncthreads();

  // gather 5: src s3 (buf0) -> s4, s5
  ldcf(cf1, wsf, 2, 2); ldcf(cf2, wsf, 2, 3);
  gather<2>(l40, b0, oi, oj, ty, tx, cf1, cf2, C, A);
  WRITEV(C, 2);
  STASHV(l41, C);                          // s4 -> buf1 (buf1 reads fenced above)
  __syncthreads();

  // gather 6: src s4 (buf1) -> s5
  ldcf(cf1, wsf, 3, 3);
  gather<1>(l41, b1, oi, oj, ty, tx, cf1, cf1, A, A);
  WRITEV(A, 3);
}

extern "C" void kernel_launch(void* const* d_in, const int* in_sizes, int n_in,
                              void* d_out, int out_size, void* d_ws, size_t ws_size,
                              hipStream_t stream) {
  (void)in_sizes; (void)n_in; (void)out_size; (void)ws_size;
  const float* x     = (const float*)d_in[0];
  const float* gamma = (const float*)d_in[1];
  const float* beta  = (const float*)d_in[2];
  const float* a_red = (const float*)d_in[4];   // reference uses alphas_reduce
  float* ws  = (float*)d_ws;
  float* out = (float*)d_out;

  stats_kernel<<<NPLANES, 256, 0, stream>>>(x, ws);
  prep_kernel<<<1, 64, 0, stream>>>(gamma, beta, a_red, ws);
  main_kernel<<<NPLANES, 1024, 0, stream>>>(x, ws, out);
}